// Round 1
// 108.214 us; speedup vs baseline: 1.0671x; 1.0671x over previous
//
#include <hip/hip_runtime.h>
#include <hip/hip_fp16.h>

#define BATCH 16
#define C_IN  64
#define HH    64
#define WW    64
#define COUT  64
#define KK    9
#define HW    4096
#define CK    576
#define MROW  200   // 192 data ushorts + 8 pad; row stride 400 B (16-B aligned)

typedef _Float16 f16x8 __attribute__((ext_vector_type(8)));
typedef float    f32x4 __attribute__((ext_vector_type(4)));

__device__ __forceinline__ unsigned short f32_to_f16u(float f) {
    _Float16 h = (_Float16)f;       // v_cvt_f16_f32, RNE
    unsigned short u;
    __builtin_memcpy(&u, &h, 2);
    return u;
}

__device__ __forceinline__ __half2 as_h2(unsigned int u) {
    __half2 r; __builtin_memcpy(&r, &u, 4); return r;
}
__device__ __forceinline__ unsigned int as_u32(__half2 v) {
    unsigned int u; __builtin_memcpy(&u, &v, 4); return u;
}

// Fused prep.  Blocks 0..1023: x (B,C,H,W) f32 -> xt (B,H,W,C) f16.
// Blocks 1024..1167: w (Cout,C,3,3) f32 -> wt in MFMA A-fragment order (f16):
//   wt[(((kc*6+ks)*4+ot)*64 + lane)*8 + j] = W[o=ot*16+(lane&15)]
//        [kk=ks*32+(lane>>4)*8+j] of chunk kc  (kk = tap*64+c, k=kc*3+tap)
__global__ __launch_bounds__(256) void prep_kernel(
    const float* __restrict__ x, const float* __restrict__ w,
    unsigned short* __restrict__ xt, unsigned short* __restrict__ wt) {
    __shared__ unsigned short tile[64][72];
    const int t = threadIdx.x;
    const int blk = blockIdx.x;
    if (blk < 1024) {
        const int b = blk >> 6, y = blk & 63;
        const float* xrow = x + ((b * 64) * 64 + y) * 64;
#pragma unroll
        for (int it = 0; it < 4; ++it) {
            const int idx = it * 256 + t;
            const int c = idx >> 4, seg = idx & 15;
            const float4 v = *(const float4*)(xrow + c * HW + seg * 4);
            tile[seg * 4 + 0][c] = f32_to_f16u(v.x);
            tile[seg * 4 + 1][c] = f32_to_f16u(v.y);
            tile[seg * 4 + 2][c] = f32_to_f16u(v.z);
            tile[seg * 4 + 3][c] = f32_to_f16u(v.w);
        }
        __syncthreads();
#pragma unroll
        for (int it = 0; it < 2; ++it) {
            const int idx = it * 256 + t;
            const int xx = idx >> 3, cs = idx & 7;
            *(int4*)&xt[((b * HW) + y * 64 + xx) * 64 + cs * 8] =
                *(const int4*)&tile[xx][cs * 8];
        }
    } else {
        const int i = (blk - 1024) * 256 + t;  // 0..36863
        const int j = i & 7;
        const int l = (i >> 3) & 63;
        const int ot = (i >> 9) & 3;
        const int r = i >> 11;           // 0..17
        const int ks = r % 6, kc = r / 6;
        const int o  = ot * 16 + (l & 15);
        const int kk = ks * 32 + (l >> 4) * 8 + j;
        const int tap = kk >> 6, c = kk & 63;
        const int k = kc * 3 + tap;
        wt[i] = f32_to_f16u(w[o * CK + c * KK + k]);
    }
}

// Main.  Block = 128 thr = 2 waves; wave owns a 16-px strip x 64 cout,
// wave-private LDS, no __syncthreads.
// R8 changes (theory: VALU-in-bfinish + gather-issue bound):
//  1. Staged tensor is f16 (not bf16): bilinear combine runs in packed
//     v_pk_fma_f16 (__hfma2) on the raw loaded words -- no unpack shifts,
//     no manual RNE pack, result is already-packed f16 for LDS.
//     (f16 10-bit mantissa > bf16 8-bit: accuracy improves.)
//  2. Gathers widened to dwordx4: 8 lanes per pixel-corner (16 B each).
//     144 -> 72 vmem instrs/wave, same bytes & same 96 in-flight VGPRs,
//     half the TA/address work, half the PWa reads.
//  3. Bilinear weights pre-packed as (w,w) half2 pairs in the prologue.
__global__ __launch_bounds__(128, 4) void dcn_main_kernel(
    const float* __restrict__ offset, const float* __restrict__ mask,
    const unsigned short* __restrict__ xt, const unsigned short* __restrict__ wt,
    const float* __restrict__ bias, float* __restrict__ out) {
    __shared__ __align__(16) unsigned short Mlds[2][16 * MROW];  // 12800 B
    __shared__ __align__(16) int PWw[2][144 * 4];                //  4608 B
    __shared__ __align__(8) unsigned short PWa[2][144 * 4];      //  2304 B

    const int t    = threadIdx.x;
    const int wave = __builtin_amdgcn_readfirstlane(t >> 6);
    const int lane = t & 63;
    const int quad = lane >> 4, m16 = lane & 15;

    const int blk = blockIdx.x;
    const int xcd = blk & 7;                    // L2 image pinning (R2 win)
    const int i8  = blk >> 3;                   // 0..255 within XCD
    const int s   = ((i8 & 31) << 3) | (i8 >> 5);  // CU-clustered strip id
    const int b   = (xcd << 1) | (s >> 7);
    const int rr  = s & 127;
    const int row = rr >> 1;
    const int qbase = (rr & 1) * 32 + wave * 16;

    f32x4 acc[4];
#pragma unroll
    for (int ot = 0; ot < 4; ++ot)
#pragma unroll
        for (int r = 0; r < 4; ++r) acc[ot][r] = 0.f;

    const float* offb = offset + b * (2 * KK * HW) + row * 64;
    const float* mb   = mask + b * (KK * HW) + row * 64;
    const char* xtb   = (const char*)(xt + b * (HW * 64));
    char* MW = (char*)Mlds[wave];
    const int lg  = lane >> 3;          // pixel-tap subgroup (8 lanes each)
    const int co2 = (lane & 7) * 16;    // 16-B channel block within a pixel

    // ---- Prologue: params for all 9 taps x 16 px -> PWw/PWa ----
#pragma unroll
    for (int p = 0; p < 3; ++p) {
        if (lane < 48) {
            const int t3  = lane >> 4;          // kx
            const int tap = p * 3 + t3;         // global tap; ky = p
            const int pxi = lane & 15;
            const int q = qbase + pxi;
            const float oy = offb[(2 * tap) * HW + q];
            const float ox = offb[(2 * tap + 1) * HW + q];
            const float mk = mb[tap * HW + q];
            const float py  = oy + (float)(row - 1 + p);
            const float pxf = ox + (float)(q - 1 + t3);
            const float y0f = floorf(py), x0f = floorf(pxf);
            const float wy = py - y0f, wx = pxf - x0f;
            const int y0 = (int)y0f, x0 = (int)x0f;
            const int y1 = y0 + 1,   x1 = x0 + 1;
            const float vy0 = (y0 >= 0 && y0 < HH) ? 1.f : 0.f;
            const float vy1 = (y1 >= 0 && y1 < HH) ? 1.f : 0.f;
            const float vx0 = (x0 >= 0 && x0 < WW) ? 1.f : 0.f;
            const float vx1 = (x1 >= 0 && x1 < WW) ? 1.f : 0.f;
            const float w00 = (1.f - wy) * (1.f - wx) * vy0 * vx0 * mk;
            const float w01 = (1.f - wy) * wx         * vy0 * vx1 * mk;
            const float w10 = wy * (1.f - wx)         * vy1 * vx0 * mk;
            const float w11 = wy * wx                 * vy1 * vx1 * mk;
            const int cy0 = min(max(y0, 0), HH - 1), cy1 = min(max(y1, 0), HH - 1);
            const int cx0 = min(max(x0, 0), WW - 1), cx1 = min(max(x1, 0), WW - 1);
            const int it = tap * 16 + pxi;
            const unsigned int s00 = f32_to_f16u(w00);
            const unsigned int s01 = f32_to_f16u(w01);
            const unsigned int s10 = f32_to_f16u(w10);
            const unsigned int s11 = f32_to_f16u(w11);
            int4 P0;
            P0.x = (int)(s00 | (s00 << 16));   // (w,w) half2 pairs
            P0.y = (int)(s01 | (s01 << 16));
            P0.z = (int)(s10 | (s10 << 16));
            P0.w = (int)(s11 | (s11 << 16));
            *(int4*)&PWw[wave][it * 4] = P0;
            ushort4 A;
            A.x = (unsigned short)(cy0 * 64 + cx0);
            A.y = (unsigned short)(cy0 * 64 + cx1);
            A.z = (unsigned short)(cy1 * 64 + cx0);
            A.w = (unsigned short)(cy1 * 64 + cx1);
            *(ushort4*)&PWa[wave][it * 4] = A;
        }
    }

    uint4 g[6][4];                   // 24 in-flight dwordx4 gathers (96 VGPR)

    auto bload = [&](int kc) {
        const unsigned short* Pa = &PWa[wave][0] + 48 * kc * 4;
#pragma unroll
        for (int i = 0; i < 6; ++i) {
            const int l = i * 8 + lg;
            const ushort4 a = *(const ushort4*)(Pa + l * 4);  // broadcast x8
            g[i][0] = *(const uint4*)(xtb + ((int)a.x << 7) + co2);
            g[i][1] = *(const uint4*)(xtb + ((int)a.y << 7) + co2);
            g[i][2] = *(const uint4*)(xtb + ((int)a.z << 7) + co2);
            g[i][3] = *(const uint4*)(xtb + ((int)a.w << 7) + co2);
        }
    };

    auto bfinish = [&](int kc) {
        const int* Pw = &PWw[wave][0] + 48 * kc * 4;
#pragma unroll
        for (int i = 0; i < 6; ++i) {
            const int l = i * 8 + lg;
            const int4 p0 = *(const int4*)(Pw + l * 4);       // broadcast x8
            const __half2 c00 = as_h2((unsigned)p0.x);
            const __half2 c01 = as_h2((unsigned)p0.y);
            const __half2 c10 = as_h2((unsigned)p0.z);
            const __half2 c11 = as_h2((unsigned)p0.w);
            const uint4 q0 = g[i][0], q1 = g[i][1], q2 = g[i][2], q3 = g[i][3];
            uint4 ov;
            {
                __half2 v = __hmul2(c00, as_h2(q0.x));
                v = __hfma2(c01, as_h2(q1.x), v);
                v = __hfma2(c10, as_h2(q2.x), v);
                v = __hfma2(c11, as_h2(q3.x), v);
                ov.x = as_u32(v);
            }
            {
                __half2 v = __hmul2(c00, as_h2(q0.y));
                v = __hfma2(c01, as_h2(q1.y), v);
                v = __hfma2(c10, as_h2(q2.y), v);
                v = __hfma2(c11, as_h2(q3.y), v);
                ov.y = as_u32(v);
            }
            {
                __half2 v = __hmul2(c00, as_h2(q0.z));
                v = __hfma2(c01, as_h2(q1.z), v);
                v = __hfma2(c10, as_h2(q2.z), v);
                v = __hfma2(c11, as_h2(q3.z), v);
                ov.z = as_u32(v);
            }
            {
                __half2 v = __hmul2(c00, as_h2(q0.w));
                v = __hfma2(c01, as_h2(q1.w), v);
                v = __hfma2(c10, as_h2(q2.w), v);
                v = __hfma2(c11, as_h2(q3.w), v);
                ov.w = as_u32(v);
            }
            *(uint4*)(MW + (l & 15) * 400 + (l >> 4) * 128 + co2) = ov;
        }
    };

    auto phaseC = [&](int kc) {
        const unsigned short* wkc = wt + kc * (6 * 4 * 512);
#pragma unroll
        for (int ks = 0; ks < 6; ++ks) {
            const f16x8 bfrag =
                *(const f16x8*)(MW + m16 * 400 + ks * 64 + quad * 16);
#pragma unroll
            for (int ot = 0; ot < 4; ++ot) {
                const f16x8 afrag =
                    *(const f16x8*)(wkc + (ks * 4 + ot) * 512 + lane * 8);
                acc[ot] = __builtin_amdgcn_mfma_f32_16x16x32_f16(afrag, bfrag,
                                                                 acc[ot], 0, 0, 0);
            }
        }
    };

    bload(0);
    __builtin_amdgcn_sched_barrier(0);   // keep gathers issued before use
    for (int kc = 0; kc < 3; ++kc) {
        bfinish(kc);
        if (kc < 2) {
            bload(kc + 1);
            __builtin_amdgcn_sched_barrier(0);
        }
        phaseC(kc);
    }

    float* ob = out + b * (COUT * HW) + row * 64 + qbase + m16;
#pragma unroll
    for (int ot = 0; ot < 4; ++ot)
#pragma unroll
        for (int r = 0; r < 4; ++r) {
            const int o = ot * 16 + quad * 4 + r;
            ob[o * HW] = acc[ot][r] + bias[o];
        }
}

extern "C" void kernel_launch(void* const* d_in, const int* in_sizes, int n_in,
                              void* d_out, int out_size, void* d_ws,
                              size_t ws_size, hipStream_t stream) {
    const float* x    = (const float*)d_in[0];
    const float* off  = (const float*)d_in[1];
    const float* mask = (const float*)d_in[2];
    const float* w    = (const float*)d_in[3];
    const float* bias = (const float*)d_in[4];
    float* out = (float*)d_out;

    unsigned short* xt = (unsigned short*)d_ws;                     // 8388608 B
    unsigned short* wt = (unsigned short*)((char*)d_ws + 8388608);  // 73728 B

    prep_kernel<<<1024 + 144, 256, 0, stream>>>(x, w, xt, wt);
    dcn_main_kernel<<<2048, 128, 0, stream>>>(off, mask, xt, wt, bias, out);
}